// Round 3
// baseline (387.969 us; speedup 1.0000x reference)
//
#include <hip/hip_runtime.h>

typedef __attribute__((ext_vector_type(4))) float f32x4;
typedef __attribute__((ext_vector_type(8))) short short8;
typedef __attribute__((ext_vector_type(8))) unsigned short u16x8;
typedef __attribute__((ext_vector_type(4))) unsigned short u16x4;
typedef __attribute__((ext_vector_type(2))) unsigned int u32x2;

#define D_MODEL 1024
#define NHEADS 16
#define T_SEQ 2048
#define M_TOT 4096   // B*T

__device__ __forceinline__ unsigned short f2bf(float f) {
    union { float f; unsigned int u; } v; v.f = f;
    return (unsigned short)((v.u + 0x7fffu + ((v.u >> 16) & 1u)) >> 16);
}
__device__ __forceinline__ float bf2f(unsigned short b) {
    union { unsigned int u; float f; } v; v.u = ((unsigned int)b) << 16;
    return v.f;
}
__device__ __forceinline__ float bcf(unsigned int u) {
    union { unsigned int u; float f; } v; v.u = u; return v.f;
}
// packed f32x2 -> bf16x2 (low = src0, high = src1)
__device__ __forceinline__ unsigned int cvtpk_bf16(float lo, float hi) {
    unsigned int r;
    asm("v_cvt_pk_bf16_f32 %0, %1, %2" : "=v"(r) : "v"(lo), "v"(hi));
    return r;
}

// ---------------- convert x fp32 -> bf16 ----------------
__global__ __launch_bounds__(256) void convert_x_kernel(const float* __restrict__ X,
                                                        unsigned short* __restrict__ Xb) {
    const int i = (blockIdx.x * 256 + threadIdx.x) * 4;
    const float4 v = *(const float4*)(X + i);
    u16x4 r;
    r.x = f2bf(v.x); r.y = f2bf(v.y); r.z = f2bf(v.z); r.w = f2bf(v.w);
    *(u16x4*)(Xb + i) = r;
}

// ---------------- 4x W [k][n] fp32 -> Wt [n][k] bf16, batched over z ----------------
__global__ __launch_bounds__(256) void transpose_w_kernel(const float* __restrict__ W0,
                                                          const float* __restrict__ W1,
                                                          const float* __restrict__ W2,
                                                          const float* __restrict__ W3,
                                                          unsigned short* __restrict__ Wt0) {
    __shared__ float tile[64][65];
    const int z = blockIdx.z;
    const float* W = (z == 0) ? W0 : (z == 1) ? W1 : (z == 2) ? W2 : W3;
    unsigned short* Wt = Wt0 + (size_t)z * D_MODEL * D_MODEL;
    const int n0 = blockIdx.x * 64, k0 = blockIdx.y * 64;
    for (int i = threadIdx.x; i < 4096; i += 256) {
        const int r = i >> 6, c = i & 63;
        tile[r][c] = W[(size_t)(k0 + r) * D_MODEL + n0 + c];
    }
    __syncthreads();
    for (int i = threadIdx.x; i < 4096; i += 256) {
        const int r = i >> 6, c = i & 63;  // r: n-local, c: k-local
        Wt[(size_t)(n0 + r) * D_MODEL + k0 + c] = f2bf(tile[c][r]);
    }
}

// ---------------- GEMM: C = A[M][1024] @ W, with Wt[n][k] pre-transposed ----------------
#define TN_G 128
#define BK_G 32
#define BKP_G 36

template<int MI, int OUTMODE>
__global__ __launch_bounds__(256) void gemm_kernel(
    const unsigned short* __restrict__ A,
    const unsigned short* __restrict__ Bt0,
    void* __restrict__ Cout0,
    const float* __restrict__ cosp,
    const float* __restrict__ sinp)
{
    constexpr int TMc = MI * 32;
    constexpr int NA = (TMc * 4) / 256;
    __shared__ unsigned short sA[TMc * BKP_G];
    __shared__ unsigned short sB[TN_G * BKP_G];

    const int tid = threadIdx.x;
    const int wid = tid >> 6;
    const int lane = tid & 63;
    const int quad = lane >> 4;
    const int l16 = lane & 15;
    const int wm = wid >> 1, wn = wid & 1;
    const int m0 = blockIdx.x * TMc, n0 = blockIdx.y * TN_G;
    const int z = blockIdx.z;
    const unsigned short* Bt = Bt0 + (size_t)z * D_MODEL * D_MODEL;

    f32x4 acc[MI][4] = {};

    for (int k0 = 0; k0 < D_MODEL; k0 += BK_G) {
        u16x8 av[NA], bv[2];
        #pragma unroll
        for (int i = 0; i < NA; ++i) {
            const int c = tid + i * 256, r = c >> 2, sg = (c & 3) * 8;
            av[i] = *(const u16x8*)(A + (size_t)(m0 + r) * D_MODEL + k0 + sg);
        }
        #pragma unroll
        for (int i = 0; i < 2; ++i) {
            const int c = tid + i * 256, r = c >> 2, sg = (c & 3) * 8;
            bv[i] = *(const u16x8*)(Bt + (size_t)(n0 + r) * D_MODEL + k0 + sg);
        }
        __syncthreads();
        #pragma unroll
        for (int i = 0; i < NA; ++i) {
            const int c = tid + i * 256, r = c >> 2, sg = (c & 3) * 8;
            *(u16x8*)&sA[r * BKP_G + sg] = av[i];
        }
        #pragma unroll
        for (int i = 0; i < 2; ++i) {
            const int c = tid + i * 256, r = c >> 2, sg = (c & 3) * 8;
            *(u16x8*)&sB[r * BKP_G + sg] = bv[i];
        }
        __syncthreads();

        short8 af[MI], bf[4];
        #pragma unroll
        for (int i = 0; i < MI; ++i)
            af[i] = *(const short8*)&sA[(wm * (MI * 16) + i * 16 + l16) * BKP_G + quad * 8];
        #pragma unroll
        for (int i = 0; i < 4; ++i)
            bf[i] = *(const short8*)&sB[(wn * 64 + i * 16 + l16) * BKP_G + quad * 8];
        #pragma unroll
        for (int mi = 0; mi < MI; ++mi)
            #pragma unroll
            for (int ni = 0; ni < 4; ++ni)
                acc[mi][ni] = __builtin_amdgcn_mfma_f32_16x16x32_bf16(af[mi], bf[ni], acc[mi][ni], 0, 0, 0);
    }

    if constexpr (OUTMODE == 0) {
        float* C = (float*)Cout0;
        #pragma unroll
        for (int mi = 0; mi < MI; ++mi) {
            const int mb = m0 + wm * (MI * 16) + mi * 16 + quad * 4;
            #pragma unroll
            for (int ni = 0; ni < 4; ++ni) {
                const int n = n0 + wn * 64 + ni * 16 + l16;
                #pragma unroll
                for (int r = 0; r < 4; ++r)
                    C[(size_t)(mb + r) * D_MODEL + n] = acc[mi][ni][r];
            }
        }
    } else {
        unsigned short* O = (unsigned short*)Cout0 + (size_t)z * M_TOT * D_MODEL;
        const int h = (n0 + wn * 64) >> 6;   // each wave's 64 cols = exactly one head
        if (z == 2) {
            // V: write transposed Vt[bh][d][t], packed u16x4 over 4 consecutive t
            #pragma unroll
            for (int mi = 0; mi < MI; ++mi) {
                const int mb = m0 + wm * (MI * 16) + mi * 16 + quad * 4;
                const int b = mb >> 11, t = mb & (T_SEQ - 1);
                #pragma unroll
                for (int ni = 0; ni < 4; ++ni) {
                    const int d = ni * 16 + l16;
                    u16x4 pk;
                    #pragma unroll
                    for (int r = 0; r < 4; ++r) pk[r] = f2bf(acc[mi][ni][r]);
                    *(u16x4*)(O + ((size_t)(b * NHEADS + h) * 64 + d) * T_SEQ + t) = pk;
                }
            }
        } else {
            const float qs = (z == 0) ? 0.125f : 1.0f;   // fold 1/sqrt(64) into Q (exact in bf16)
            #pragma unroll
            for (int mi = 0; mi < MI; ++mi) {
                #pragma unroll
                for (int r = 0; r < 4; ++r) {
                    const int m = m0 + wm * (MI * 16) + mi * 16 + quad * 4 + r;
                    const int b = m >> 11, t = m & (T_SEQ - 1);
                    const size_t rowoff = ((size_t)(b * NHEADS + h) * T_SEQ + t) * 64;
                    #pragma unroll
                    for (int ni = 0; ni < 2; ++ni) {
                        const int d = ni * 16 + l16;           // 0..31
                        const float c = cosp[t * 32 + d], s = sinp[t * 32 + d];
                        const float x1 = acc[mi][ni][r], x2 = acc[mi][ni + 2][r];
                        O[rowoff + d]      = f2bf((x1 * c - x2 * s) * qs);
                        O[rowoff + d + 32] = f2bf((x1 * s + x2 * c) * qs);
                    }
                }
            }
        }
    }
}

// ---------------- K row-norm segment maxes: Kseg[bh][8] = max ||k_row|| over 256-row segs ----------------
__global__ __launch_bounds__(256) void kmax_kernel(const unsigned short* __restrict__ Kg,
                                                   float* __restrict__ Kseg) {
    __shared__ float red[4];
    const int seg = blockIdx.x, bh = blockIdx.y;
    const unsigned short* Kp = Kg + ((size_t)bh * T_SEQ + seg * 256) * 64;
    const int row = threadIdx.x;   // one row per thread
    const u16x8* rp = (const u16x8*)(Kp + (size_t)row * 64);
    float s = 0.f;
    #pragma unroll
    for (int c = 0; c < 8; ++c) {
        const u16x8 v = rp[c];
        #pragma unroll
        for (int e = 0; e < 8; ++e) { const float f = bf2f(v[e]); s += f * f; }
    }
    #pragma unroll
    for (int off = 32; off >= 1; off >>= 1) s = fmaxf(s, __shfl_xor(s, off));
    if ((threadIdx.x & 63) == 0) red[threadIdx.x >> 6] = s;
    __syncthreads();
    if (threadIdx.x == 0)
        Kseg[bh * 8 + seg] = __builtin_sqrtf(fmaxf(fmaxf(red[0], red[1]), fmaxf(red[2], red[3])));
}

// ---------------- flash attention (causal): SINGLE-PASS, Cauchy-Schwarz max bound ----------------
// m_hat = ||q_row|| * max_j ||k_j|| >= max s  (softmax shift-invariant -> exact math).
// p = exp2(s*log2e - m_hat*log2e) <= 1 structurally; underflow impossible.
//
// R3: SWAPPED QK^T: sT = mfma(K, Q) so each lane owns ONE q-row (l16).
//  - mL / l become per-lane scalars (no shuffle gathers in the loop)
//  - P is k-contiguous per lane -> v_cvt_pk_bf16_f32 pack + 4x ds_write_b64 per tile
//    (replaces 16 scalar f2bf + 16 ds_write_b16); l accumulates the ROUNDED p
//    (numerator/denominator bias cancels)
//  - 128-thr blocks (2 waves: j-parity pair for one w4 row-slice). grid 2048 =
//    exactly 8 blocks/CU at the 4-wave/SIMD VGPR tier; per-CU x-mix kills the
//    trip-count tail. launch_bounds 2nd arg empirically = min BLOCKS/CU
//    (R1: (512,4)->64 VGPR; R2: (512,2)->108): (128,8) -> 128-reg cap.
#define LDPP 72    // P row pitch in u16 (144 B = 9*16: b128-aligned rows, bank-spread)
#define LOG2E 1.44269504f

union alignas(16) AttnSmem {
    unsigned short P[2][2][16 * LDPP];  // [wave][tile(A,B)][16 rows x 72] = 9216 B
    float comb[64][34];                 // 8704 B: half=1 partials (O 32 + lA + lB)
};

__global__ __launch_bounds__(128, 8) void attn_kernel(
    const unsigned short* __restrict__ Q,    // [bh][t][64] bf16, RoPE'd, pre-scaled 0.125
    const unsigned short* __restrict__ Kg,   // [bh][t][64] bf16, RoPE'd
    const unsigned short* __restrict__ Vt,   // [bh][d][t]  bf16 (transposed)
    const float* __restrict__ Kseg,          // [bh][8] segment maxes of ||k||
    unsigned short* __restrict__ Z)          // [m][h*64+d] bf16
{
    __shared__ AttnSmem sm;

    const int tid = threadIdx.x;
    const int half = tid >> 6;       // wave 0: even j, wave 1: odd j
    const int lane = tid & 63;
    const int quad = lane >> 4;
    const int l16 = lane & 15;

    // mapping: XCD-local bh (L2 affinity) + per-CU stride-2 x spread (tail mixing).
    // flat -> xcd (0..7), idx (0..255); idx = t*32 + c; c = 2m + b;
    // x = 2t + b (0..15), bh = xcd*4 + (m&3), w4 = m>>2.
    const int flat = blockIdx.x;               // 0..2047
    const int xcd = flat & 7;
    const int idx = flat >> 3;                 // 0..255
    const int t8 = idx >> 5;                   // 0..7
    const int c32 = idx & 31;
    const int b1 = c32 & 1;
    const int m16 = c32 >> 1;                  // 0..15
    const int x = 2 * t8 + b1;                 // 0..15
    const int bh = xcd * 4 + (m16 & 3);        // 0..31
    const int w4 = m16 >> 2;                   // 0..3 row-slice

    const int qA = x, qB = 31 - x;       // paired q-tiles: work = 33 tiles, near-uniform
    const int jend = 31 - x;             // kv tiles 0..jend cover both

    const unsigned short* Qp = Q + (size_t)bh * T_SEQ * 64;
    const unsigned short* Kp = Kg + (size_t)bh * T_SEQ * 64;
    const unsigned short* Vp = Vt + (size_t)bh * 64 * T_SEQ;

    // Q frags (B-operand in swapped QK): row = qt*64 + w4*16 + l16, k = ks*32 + quad*8
    short8 aqA[2], aqB[2];
    {
        const unsigned short* qr = Qp + (size_t)(qA * 64 + w4 * 16 + l16) * 64 + quad * 8;
        aqA[0] = *(const short8*)(qr);
        aqA[1] = *(const short8*)(qr + 32);
        qr = Qp + (size_t)(qB * 64 + w4 * 16 + l16) * 64 + quad * 8;
        aqB[0] = *(const short8*)(qr);
        aqB[1] = *(const short8*)(qr + 32);
    }

    // max bound: per-lane scalar for q-row l16 (swapped layout: lane = q-row)
    float kmx = 0.f;
    #pragma unroll
    for (int i = 0; i < 8; ++i) kmx = fmaxf(kmx, Kseg[bh * 8 + i]);

    float mQA, mQB;
    {
        float nqA = 0.f, nqB = 0.f;
        #pragma unroll
        for (int i = 0; i < 2; ++i)
            #pragma unroll
            for (int e = 0; e < 8; ++e) {
                const float fa = bf2f((unsigned short)aqA[i][e]);
                const float fb = bf2f((unsigned short)aqB[i][e]);
                nqA += fa * fa; nqB += fb * fb;
            }
        nqA += __shfl_xor(nqA, 16); nqA += __shfl_xor(nqA, 32);
        nqB += __shfl_xor(nqB, 16); nqB += __shfl_xor(nqB, 32);
        mQA = __builtin_sqrtf(nqA) * kmx * LOG2E;
        mQB = __builtin_sqrtf(nqB) * kmx * LOG2E;
    }

    // direct-from-global fragment base addresses (per lane)
    const unsigned short* Kfb = Kp + (size_t)l16 * 64 + quad * 8;
    const unsigned short* Vfb = Vp + (size_t)l16 * T_SEQ + quad * 8;

    // swapped-QK tile: mask (k = nt*16+quad*4+r vs q = w4*16+l16), exp, cvt_pk pack,
    // l += rounded p, 4x ds_write_b64
    auto tile_pack = [&](f32x4 (&s)[4], float mQ, float& lsum, bool msk,
                         unsigned short* Pw) {
        if (msk) {
            #pragma unroll
            for (int nt = 0; nt < 4; ++nt)
                #pragma unroll
                for (int r = 0; r < 4; ++r)
                    if (nt * 16 + quad * 4 + r > w4 * 16 + l16) s[nt][r] = -1e30f;
        }
        #pragma unroll
        for (int nt = 0; nt < 4; ++nt) {
            const float p0 = __builtin_exp2f(s[nt][0] * LOG2E - mQ);
            const float p1 = __builtin_exp2f(s[nt][1] * LOG2E - mQ);
            const float p2 = __builtin_exp2f(s[nt][2] * LOG2E - mQ);
            const float p3 = __builtin_exp2f(s[nt][3] * LOG2E - mQ);
            const unsigned int w0 = cvtpk_bf16(p0, p1);
            const unsigned int w1 = cvtpk_bf16(p2, p3);
            lsum += bcf(w0 << 16) + bcf(w0 & 0xffff0000u)
                  + bcf(w1 << 16) + bcf(w1 & 0xffff0000u);
            *(u32x2*)&Pw[(size_t)l16 * LDPP + nt * 16 + quad * 4] = (u32x2){w0, w1};
        }
    };

    f32x4 oA[4] = {}, oB[4] = {};
    float lA = 0.f, lB = 0.f;
    unsigned short* PwA = &sm.P[half][0][0];
    unsigned short* PwB = &sm.P[half][1][0];

    for (int j = half; j <= jend; j += 2) {
        const bool doA = (j <= x);

        // K frags first (QK waits only on these)
        short8 kf[4][2];
        #pragma unroll
        for (int nt = 0; nt < 4; ++nt)
            #pragma unroll
            for (int ks = 0; ks < 2; ++ks)
                kf[nt][ks] = *(const short8*)(Kfb + (size_t)(j * 64 + nt * 16) * 64 + ks * 32);

        // QK-A (swapped: lane = q-row), pack A (frees sA before sB lives)
        if (doA) {
            f32x4 sA[4] = {};
            #pragma unroll
            for (int nt = 0; nt < 4; ++nt) {
                sA[nt] = __builtin_amdgcn_mfma_f32_16x16x32_bf16(kf[nt][0], aqA[0], sA[nt], 0, 0, 0);
                sA[nt] = __builtin_amdgcn_mfma_f32_16x16x32_bf16(kf[nt][1], aqA[1], sA[nt], 0, 0, 0);
            }
            tile_pack(sA, mQA, lA, j == x, PwA);
        }

        // QK-B (kf dead after this)
        f32x4 sB[4] = {};
        #pragma unroll
        for (int nt = 0; nt < 4; ++nt) {
            sB[nt] = __builtin_amdgcn_mfma_f32_16x16x32_bf16(kf[nt][0], aqB[0], sB[nt], 0, 0, 0);
            sB[nt] = __builtin_amdgcn_mfma_f32_16x16x32_bf16(kf[nt][1], aqB[1], sB[nt], 0, 0, 0);
        }

        // V frags: issued here so pack-B + lgkm + pfA-read hide their latency
        short8 vf[4][2];
        #pragma unroll
        for (int dt = 0; dt < 4; ++dt)
            #pragma unroll
            for (int ks = 0; ks < 2; ++ks)
                vf[dt][ks] = *(const short8*)(Vfb + (size_t)(dt * 16) * T_SEQ + j * 64 + ks * 32);

        tile_pack(sB, mQB, lB, j == jend, PwB);
        asm volatile("s_waitcnt lgkmcnt(0)" ::: "memory");

        if (doA) {
            short8 pf0 = *(const short8*)&PwA[(size_t)l16 * LDPP + quad * 8];
            short8 pf1 = *(const short8*)&PwA[(size_t)l16 * LDPP + 32 + quad * 8];
            #pragma unroll
            for (int dt = 0; dt < 4; ++dt) {
                oA[dt] = __builtin_amdgcn_mfma_f32_16x16x32_bf16(pf0, vf[dt][0], oA[dt], 0, 0, 0);
                oA[dt] = __builtin_amdgcn_mfma_f32_16x16x32_bf16(pf1, vf[dt][1], oA[dt], 0, 0, 0);
            }
        }
        {
            short8 pf0 = *(const short8*)&PwB[(size_t)l16 * LDPP + quad * 8];
            short8 pf1 = *(const short8*)&PwB[(size_t)l16 * LDPP + 32 + quad * 8];
            #pragma unroll
            for (int dt = 0; dt < 4; ++dt) {
                oB[dt] = __builtin_amdgcn_mfma_f32_16x16x32_bf16(pf0, vf[dt][0], oB[dt], 0, 0, 0);
                oB[dt] = __builtin_amdgcn_mfma_f32_16x16x32_bf16(pf1, vf[dt][1], oB[dt], 0, 0, 0);
            }
        }
        // no barrier in loop: P regions are per-wave
    }

    // per-half row totals (row = l16): reduce across quads
    lA += __shfl_xor(lA, 16); lA += __shfl_xor(lA, 32);
    lB += __shfl_xor(lB, 16); lB += __shfl_xor(lB, 32);

    // combine halves: fixed m_hat => partials add directly
    __syncthreads();          // both waves done with sm.P before comb overwrites it
    if (half) {
        float* cb = &sm.comb[lane][0];
        #pragma unroll
        for (int dt = 0; dt < 4; ++dt)
            #pragma unroll
            for (int r = 0; r < 4; ++r) {
                cb[dt * 4 + r]      = oA[dt][r];
                cb[16 + dt * 4 + r] = oB[dt][r];
            }
        cb[32] = lA; cb[33] = lB;
    }
    __syncthreads();
    if (half) return;

    {
        const float* cb = &sm.comb[lane][0];
        #pragma unroll
        for (int dt = 0; dt < 4; ++dt)
            #pragma unroll
            for (int r = 0; r < 4; ++r) {
                oA[dt][r] += cb[dt * 4 + r];
                oB[dt][r] += cb[16 + dt * 4 + r];
            }
        lA += cb[32]; lB += cb[33];
    }

    // invert per-lane (row l16), then gather to C-rows (quad*4+r)
    const float iA = 1.f / lA, iB = 1.f / lB;
    float irA[4], irB[4];
    #pragma unroll
    for (int r = 0; r < 4; ++r) {
        const int src = (lane & 48) | (quad * 4 + r);
        irA[r] = __shfl(iA, src);
        irB[r] = __shfl(iB, src);
    }

    // epilogue: normalize and write
    const int h = bh & 15, b = bh >> 4;
    #pragma unroll
    for (int dt = 0; dt < 4; ++dt)
        #pragma unroll
        for (int r = 0; r < 4; ++r) {
            const int rowA = qA * 64 + w4 * 16 + quad * 4 + r;
            const int rowB = qB * 64 + w4 * 16 + quad * 4 + r;
            const int col = h * 64 + dt * 16 + l16;
            Z[((size_t)b * T_SEQ + rowA) * D_MODEL + col] = f2bf(oA[dt][r] * irA[r]);
            Z[((size_t)b * T_SEQ + rowB) * D_MODEL + col] = f2bf(oB[dt][r] * irB[r]);
        }
}

// ---------------- launcher ----------------
extern "C" void kernel_launch(void* const* d_in, const int* in_sizes, int n_in,
                              void* d_out, int out_size, void* d_ws, size_t ws_size,
                              hipStream_t stream) {
    const float* x    = (const float*)d_in[0];
    const float* cosp = (const float*)d_in[1];
    const float* sinp = (const float*)d_in[2];
    const float* Wq   = (const float*)d_in[3];
    const float* Wk   = (const float*)d_in[4];
    const float* Wv   = (const float*)d_in[5];
    const float* Wo   = (const float*)d_in[6];

    char* w = (char*)d_ws;
    unsigned short* xb  = (unsigned short*)w; w += (size_t)M_TOT * D_MODEL * 2;    // 8 MB
    unsigned short* wt  = (unsigned short*)w; w += (size_t)4 * D_MODEL * D_MODEL * 2; // 8 MB (q,k,v,o)
    unsigned short* Qb  = (unsigned short*)w; w += (size_t)M_TOT * D_MODEL * 2;    // 8 MB
    unsigned short* Kb  = (unsigned short*)w; w += (size_t)M_TOT * D_MODEL * 2;
    unsigned short* Vtb = (unsigned short*)w; w += (size_t)M_TOT * D_MODEL * 2;    // [bh][d][t]
    unsigned short* Zb  = (unsigned short*)w; w += (size_t)M_TOT * D_MODEL * 2;
    float*          Ks  = (float*)w;          w += 32 * 8 * sizeof(float);         // Kseg[bh][8]

    convert_x_kernel<<<(M_TOT * D_MODEL) / 1024, 256, 0, stream>>>(x, xb);
    transpose_w_kernel<<<dim3(16, 16, 4), 256, 0, stream>>>(Wq, Wk, Wv, Wo, wt);

    // fused QKV projection; epilogue: z=0 Q(RoPE,*0.125), z=1 K(RoPE), z=2 V(transposed)
    gemm_kernel<4, 1><<<dim3(M_TOT / 128, D_MODEL / 128, 3), 256, 0, stream>>>(
        xb, wt, (void*)Qb, cosp, sinp);

    kmax_kernel<<<dim3(8, 32), 256, 0, stream>>>(Kb, Ks);

    // 128-thr blocks (2 waves: j-parity pair for one w4 slice), grid 2048 = 8 blocks/CU
    attn_kernel<<<2048, 128, 0, stream>>>(Qb, Kb, Vtb, Ks, Zb);

    // out projection -> fp32 d_out
    gemm_kernel<2, 0><<<dim3(M_TOT / 64, D_MODEL / 128, 1), 256, 0, stream>>>(
        Zb, wt + (size_t)3 * D_MODEL * D_MODEL, d_out, nullptr, nullptr);
}

// Round 4
// 257.046 us; speedup vs baseline: 1.5093x; 1.5093x over previous
//
#include <hip/hip_runtime.h>

typedef __attribute__((ext_vector_type(4))) float f32x4;
typedef __attribute__((ext_vector_type(8))) short short8;
typedef __attribute__((ext_vector_type(8))) unsigned short u16x8;
typedef __attribute__((ext_vector_type(4))) unsigned short u16x4;
typedef __attribute__((ext_vector_type(2))) unsigned int u32x2;

#define D_MODEL 1024
#define NHEADS 16
#define T_SEQ 2048
#define M_TOT 4096   // B*T

__device__ __forceinline__ unsigned short f2bf(float f) {
    union { float f; unsigned int u; } v; v.f = f;
    return (unsigned short)((v.u + 0x7fffu + ((v.u >> 16) & 1u)) >> 16);
}
__device__ __forceinline__ float bf2f(unsigned short b) {
    union { unsigned int u; float f; } v; v.u = ((unsigned int)b) << 16;
    return v.f;
}
__device__ __forceinline__ float bcf(unsigned int u) {
    union { unsigned int u; float f; } v; v.u = u; return v.f;
}
// packed f32x2 -> bf16x2 (low = src0, high = src1)
__device__ __forceinline__ unsigned int cvtpk_bf16(float lo, float hi) {
    unsigned int r;
    asm("v_cvt_pk_bf16_f32 %0, %1, %2" : "=v"(r) : "v"(lo), "v"(hi));
    return r;
}

// ---------------- convert x fp32 -> bf16 ----------------
__global__ __launch_bounds__(256) void convert_x_kernel(const float* __restrict__ X,
                                                        unsigned short* __restrict__ Xb) {
    const int i = (blockIdx.x * 256 + threadIdx.x) * 4;
    const float4 v = *(const float4*)(X + i);
    u16x4 r;
    r.x = f2bf(v.x); r.y = f2bf(v.y); r.z = f2bf(v.z); r.w = f2bf(v.w);
    *(u16x4*)(Xb + i) = r;
}

// ---------------- 4x W [k][n] fp32 -> Wt [n][k] bf16, batched over z ----------------
__global__ __launch_bounds__(256) void transpose_w_kernel(const float* __restrict__ W0,
                                                          const float* __restrict__ W1,
                                                          const float* __restrict__ W2,
                                                          const float* __restrict__ W3,
                                                          unsigned short* __restrict__ Wt0) {
    __shared__ float tile[64][65];
    const int z = blockIdx.z;
    const float* W = (z == 0) ? W0 : (z == 1) ? W1 : (z == 2) ? W2 : W3;
    unsigned short* Wt = Wt0 + (size_t)z * D_MODEL * D_MODEL;
    const int n0 = blockIdx.x * 64, k0 = blockIdx.y * 64;
    for (int i = threadIdx.x; i < 4096; i += 256) {
        const int r = i >> 6, c = i & 63;
        tile[r][c] = W[(size_t)(k0 + r) * D_MODEL + n0 + c];
    }
    __syncthreads();
    for (int i = threadIdx.x; i < 4096; i += 256) {
        const int r = i >> 6, c = i & 63;  // r: n-local, c: k-local
        Wt[(size_t)(n0 + r) * D_MODEL + k0 + c] = f2bf(tile[c][r]);
    }
}

// ---------------- GEMM: C = A[M][1024] @ W, with Wt[n][k] pre-transposed ----------------
#define TN_G 128
#define BK_G 32
#define BKP_G 36

template<int MI, int OUTMODE>
__global__ __launch_bounds__(256) void gemm_kernel(
    const unsigned short* __restrict__ A,
    const unsigned short* __restrict__ Bt0,
    void* __restrict__ Cout0,
    const float* __restrict__ cosp,
    const float* __restrict__ sinp)
{
    constexpr int TMc = MI * 32;
    constexpr int NA = (TMc * 4) / 256;
    __shared__ unsigned short sA[TMc * BKP_G];
    __shared__ unsigned short sB[TN_G * BKP_G];

    const int tid = threadIdx.x;
    const int wid = tid >> 6;
    const int lane = tid & 63;
    const int quad = lane >> 4;
    const int l16 = lane & 15;
    const int wm = wid >> 1, wn = wid & 1;
    const int m0 = blockIdx.x * TMc, n0 = blockIdx.y * TN_G;
    const int z = blockIdx.z;
    const unsigned short* Bt = Bt0 + (size_t)z * D_MODEL * D_MODEL;

    f32x4 acc[MI][4] = {};

    for (int k0 = 0; k0 < D_MODEL; k0 += BK_G) {
        u16x8 av[NA], bv[2];
        #pragma unroll
        for (int i = 0; i < NA; ++i) {
            const int c = tid + i * 256, r = c >> 2, sg = (c & 3) * 8;
            av[i] = *(const u16x8*)(A + (size_t)(m0 + r) * D_MODEL + k0 + sg);
        }
        #pragma unroll
        for (int i = 0; i < 2; ++i) {
            const int c = tid + i * 256, r = c >> 2, sg = (c & 3) * 8;
            bv[i] = *(const u16x8*)(Bt + (size_t)(n0 + r) * D_MODEL + k0 + sg);
        }
        __syncthreads();
        #pragma unroll
        for (int i = 0; i < NA; ++i) {
            const int c = tid + i * 256, r = c >> 2, sg = (c & 3) * 8;
            *(u16x8*)&sA[r * BKP_G + sg] = av[i];
        }
        #pragma unroll
        for (int i = 0; i < 2; ++i) {
            const int c = tid + i * 256, r = c >> 2, sg = (c & 3) * 8;
            *(u16x8*)&sB[r * BKP_G + sg] = bv[i];
        }
        __syncthreads();

        short8 af[MI], bf[4];
        #pragma unroll
        for (int i = 0; i < MI; ++i)
            af[i] = *(const short8*)&sA[(wm * (MI * 16) + i * 16 + l16) * BKP_G + quad * 8];
        #pragma unroll
        for (int i = 0; i < 4; ++i)
            bf[i] = *(const short8*)&sB[(wn * 64 + i * 16 + l16) * BKP_G + quad * 8];
        #pragma unroll
        for (int mi = 0; mi < MI; ++mi)
            #pragma unroll
            for (int ni = 0; ni < 4; ++ni)
                acc[mi][ni] = __builtin_amdgcn_mfma_f32_16x16x32_bf16(af[mi], bf[ni], acc[mi][ni], 0, 0, 0);
    }

    if constexpr (OUTMODE == 0) {
        float* C = (float*)Cout0;
        #pragma unroll
        for (int mi = 0; mi < MI; ++mi) {
            const int mb = m0 + wm * (MI * 16) + mi * 16 + quad * 4;
            #pragma unroll
            for (int ni = 0; ni < 4; ++ni) {
                const int n = n0 + wn * 64 + ni * 16 + l16;
                #pragma unroll
                for (int r = 0; r < 4; ++r)
                    C[(size_t)(mb + r) * D_MODEL + n] = acc[mi][ni][r];
            }
        }
    } else {
        unsigned short* O = (unsigned short*)Cout0 + (size_t)z * M_TOT * D_MODEL;
        const int h = (n0 + wn * 64) >> 6;   // each wave's 64 cols = exactly one head
        if (z == 2) {
            // V: write transposed Vt[bh][d][t], packed u16x4 over 4 consecutive t
            #pragma unroll
            for (int mi = 0; mi < MI; ++mi) {
                const int mb = m0 + wm * (MI * 16) + mi * 16 + quad * 4;
                const int b = mb >> 11, t = mb & (T_SEQ - 1);
                #pragma unroll
                for (int ni = 0; ni < 4; ++ni) {
                    const int d = ni * 16 + l16;
                    u16x4 pk;
                    #pragma unroll
                    for (int r = 0; r < 4; ++r) pk[r] = f2bf(acc[mi][ni][r]);
                    *(u16x4*)(O + ((size_t)(b * NHEADS + h) * 64 + d) * T_SEQ + t) = pk;
                }
            }
        } else {
            const float qs = (z == 0) ? 0.125f : 1.0f;   // fold 1/sqrt(64) into Q (exact in bf16)
            #pragma unroll
            for (int mi = 0; mi < MI; ++mi) {
                #pragma unroll
                for (int r = 0; r < 4; ++r) {
                    const int m = m0 + wm * (MI * 16) + mi * 16 + quad * 4 + r;
                    const int b = m >> 11, t = m & (T_SEQ - 1);
                    const size_t rowoff = ((size_t)(b * NHEADS + h) * T_SEQ + t) * 64;
                    #pragma unroll
                    for (int ni = 0; ni < 2; ++ni) {
                        const int d = ni * 16 + l16;           // 0..31
                        const float c = cosp[t * 32 + d], s = sinp[t * 32 + d];
                        const float x1 = acc[mi][ni][r], x2 = acc[mi][ni + 2][r];
                        O[rowoff + d]      = f2bf((x1 * c - x2 * s) * qs);
                        O[rowoff + d + 32] = f2bf((x1 * s + x2 * c) * qs);
                    }
                }
            }
        }
    }
}

// ---------------- K row-norm segment maxes: Kseg[bh][8] = max ||k_row|| over 256-row segs ----------------
__global__ __launch_bounds__(256) void kmax_kernel(const unsigned short* __restrict__ Kg,
                                                   float* __restrict__ Kseg) {
    __shared__ float red[4];
    const int seg = blockIdx.x, bh = blockIdx.y;
    const unsigned short* Kp = Kg + ((size_t)bh * T_SEQ + seg * 256) * 64;
    const int row = threadIdx.x;   // one row per thread
    const u16x8* rp = (const u16x8*)(Kp + (size_t)row * 64);
    float s = 0.f;
    #pragma unroll
    for (int c = 0; c < 8; ++c) {
        const u16x8 v = rp[c];
        #pragma unroll
        for (int e = 0; e < 8; ++e) { const float f = bf2f(v[e]); s += f * f; }
    }
    #pragma unroll
    for (int off = 32; off >= 1; off >>= 1) s = fmaxf(s, __shfl_xor(s, off));
    if ((threadIdx.x & 63) == 0) red[threadIdx.x >> 6] = s;
    __syncthreads();
    if (threadIdx.x == 0)
        Kseg[bh * 8 + seg] = __builtin_sqrtf(fmaxf(fmaxf(red[0], red[1]), fmaxf(red[2], red[3])));
}

// ---------------- flash attention (causal): SINGLE-PASS, Cauchy-Schwarz max bound ----------------
// m_hat = ||q_row|| * max_j ||k_j|| >= max s  (softmax shift-invariant -> exact math).
// p = exp2(s*log2e - m_hat*log2e) <= 1 structurally; underflow impossible.
//
// Swapped QK^T (sT = mfma(K, Q)): each lane owns ONE q-row (l16); mL/l are per-lane
// scalars; P packs via v_cvt_pk_bf16_f32 + 4x ds_write_b64 per tile; l accumulates
// the ROUNDED p (numerator/denominator bias cancels). 128-thr blocks (2 waves:
// j-parity pair), grid 2048; per-CU x-mix kills the trip-count tail.
//
// LAUNCH_BOUNDS LAW (measured R1/R2/R3): VGPR cap = 256 / second_arg, INDEPENDENT
// of block size ((512,4)->64, (512,2)->128(108 used), (128,8)->32). Body needs
// ~110 regs => arg MUST be 2. R3's arg=8 forced a 32-reg budget -> 555 MB scratch
// spills -> HBM-bound at 231us.
#define LDPP 72    // P row pitch in u16 (144 B = 9*16: b128-aligned rows, 2-way banks = free)
#define LOG2E 1.44269504f

union alignas(16) AttnSmem {
    unsigned short P[2][2][16 * LDPP];  // [wave][tile(A,B)][16 rows x 72] = 9216 B
    float comb[64][34];                 // 8704 B: half=1 partials (O 32 + lA + lB)
};

__global__ __launch_bounds__(128, 2) void attn_kernel(
    const unsigned short* __restrict__ Q,    // [bh][t][64] bf16, RoPE'd, pre-scaled 0.125
    const unsigned short* __restrict__ Kg,   // [bh][t][64] bf16, RoPE'd
    const unsigned short* __restrict__ Vt,   // [bh][d][t]  bf16 (transposed)
    const float* __restrict__ Kseg,          // [bh][8] segment maxes of ||k||
    unsigned short* __restrict__ Z)          // [m][h*64+d] bf16
{
    __shared__ AttnSmem sm;

    const int tid = threadIdx.x;
    const int half = tid >> 6;       // wave 0: even j, wave 1: odd j
    const int lane = tid & 63;
    const int quad = lane >> 4;
    const int l16 = lane & 15;

    // mapping: XCD-local bh (L2 affinity) + per-CU stride-2 x spread (tail mixing).
    const int flat = blockIdx.x;               // 0..2047
    const int xcd = flat & 7;
    const int idx = flat >> 3;                 // 0..255
    const int t8 = idx >> 5;                   // 0..7
    const int c32 = idx & 31;
    const int b1 = c32 & 1;
    const int m16 = c32 >> 1;                  // 0..15
    const int x = 2 * t8 + b1;                 // 0..15
    const int bh = xcd * 4 + (m16 & 3);        // 0..31
    const int w4 = m16 >> 2;                   // 0..3 row-slice

    const int qA = x, qB = 31 - x;       // paired q-tiles: work = 33 tiles, near-uniform
    const int jend = 31 - x;             // kv tiles 0..jend cover both

    const unsigned short* Qp = Q + (size_t)bh * T_SEQ * 64;
    const unsigned short* Kp = Kg + (size_t)bh * T_SEQ * 64;
    const unsigned short* Vp = Vt + (size_t)bh * 64 * T_SEQ;

    // Q frags (B-operand in swapped QK): row = qt*64 + w4*16 + l16, k = ks*32 + quad*8
    short8 aqA[2], aqB[2];
    {
        const unsigned short* qr = Qp + (size_t)(qA * 64 + w4 * 16 + l16) * 64 + quad * 8;
        aqA[0] = *(const short8*)(qr);
        aqA[1] = *(const short8*)(qr + 32);
        qr = Qp + (size_t)(qB * 64 + w4 * 16 + l16) * 64 + quad * 8;
        aqB[0] = *(const short8*)(qr);
        aqB[1] = *(const short8*)(qr + 32);
    }

    // max bound: per-lane scalar for q-row l16 (swapped layout: lane = q-row)
    float kmx = 0.f;
    #pragma unroll
    for (int i = 0; i < 8; ++i) kmx = fmaxf(kmx, Kseg[bh * 8 + i]);

    float mQA, mQB;
    {
        float nqA = 0.f, nqB = 0.f;
        #pragma unroll
        for (int i = 0; i < 2; ++i)
            #pragma unroll
            for (int e = 0; e < 8; ++e) {
                const float fa = bf2f((unsigned short)aqA[i][e]);
                const float fb = bf2f((unsigned short)aqB[i][e]);
                nqA += fa * fa; nqB += fb * fb;
            }
        nqA += __shfl_xor(nqA, 16); nqA += __shfl_xor(nqA, 32);
        nqB += __shfl_xor(nqB, 16); nqB += __shfl_xor(nqB, 32);
        mQA = __builtin_sqrtf(nqA) * kmx * LOG2E;
        mQB = __builtin_sqrtf(nqB) * kmx * LOG2E;
    }

    // direct-from-global fragment base addresses (per lane)
    const unsigned short* Kfb = Kp + (size_t)l16 * 64 + quad * 8;
    const unsigned short* Vfb = Vp + (size_t)l16 * T_SEQ + quad * 8;

    // swapped-QK tile: mask (k = nt*16+quad*4+r vs q = w4*16+l16), exp, cvt_pk pack,
    // l += rounded p, 4x ds_write_b64
    auto tile_pack = [&](f32x4 (&s)[4], float mQ, float& lsum, bool msk,
                         unsigned short* Pw) {
        if (msk) {
            #pragma unroll
            for (int nt = 0; nt < 4; ++nt)
                #pragma unroll
                for (int r = 0; r < 4; ++r)
                    if (nt * 16 + quad * 4 + r > w4 * 16 + l16) s[nt][r] = -1e30f;
        }
        #pragma unroll
        for (int nt = 0; nt < 4; ++nt) {
            const float p0 = __builtin_exp2f(s[nt][0] * LOG2E - mQ);
            const float p1 = __builtin_exp2f(s[nt][1] * LOG2E - mQ);
            const float p2 = __builtin_exp2f(s[nt][2] * LOG2E - mQ);
            const float p3 = __builtin_exp2f(s[nt][3] * LOG2E - mQ);
            const unsigned int w0 = cvtpk_bf16(p0, p1);
            const unsigned int w1 = cvtpk_bf16(p2, p3);
            lsum += bcf(w0 << 16) + bcf(w0 & 0xffff0000u)
                  + bcf(w1 << 16) + bcf(w1 & 0xffff0000u);
            *(u32x2*)&Pw[(size_t)l16 * LDPP + nt * 16 + quad * 4] = (u32x2){w0, w1};
        }
    };

    f32x4 oA[4] = {}, oB[4] = {};
    float lA = 0.f, lB = 0.f;
    unsigned short* PwA = &sm.P[half][0][0];
    unsigned short* PwB = &sm.P[half][1][0];

    for (int j = half; j <= jend; j += 2) {
        const bool doA = (j <= x);

        // K frags first (QK waits only on these)
        short8 kf[4][2];
        #pragma unroll
        for (int nt = 0; nt < 4; ++nt)
            #pragma unroll
            for (int ks = 0; ks < 2; ++ks)
                kf[nt][ks] = *(const short8*)(Kfb + (size_t)(j * 64 + nt * 16) * 64 + ks * 32);

        // QK-A (swapped: lane = q-row), pack A (frees sA before sB lives)
        if (doA) {
            f32x4 sA[4] = {};
            #pragma unroll
            for (int nt = 0; nt < 4; ++nt) {
                sA[nt] = __builtin_amdgcn_mfma_f32_16x16x32_bf16(kf[nt][0], aqA[0], sA[nt], 0, 0, 0);
                sA[nt] = __builtin_amdgcn_mfma_f32_16x16x32_bf16(kf[nt][1], aqA[1], sA[nt], 0, 0, 0);
            }
            tile_pack(sA, mQA, lA, j == x, PwA);
        }

        // QK-B (kf dead after this)
        f32x4 sB[4] = {};
        #pragma unroll
        for (int nt = 0; nt < 4; ++nt) {
            sB[nt] = __builtin_amdgcn_mfma_f32_16x16x32_bf16(kf[nt][0], aqB[0], sB[nt], 0, 0, 0);
            sB[nt] = __builtin_amdgcn_mfma_f32_16x16x32_bf16(kf[nt][1], aqB[1], sB[nt], 0, 0, 0);
        }

        // V frags: issued here so pack-B + lgkm + pfA-read hide their latency
        short8 vf[4][2];
        #pragma unroll
        for (int dt = 0; dt < 4; ++dt)
            #pragma unroll
            for (int ks = 0; ks < 2; ++ks)
                vf[dt][ks] = *(const short8*)(Vfb + (size_t)(dt * 16) * T_SEQ + j * 64 + ks * 32);

        tile_pack(sB, mQB, lB, j == jend, PwB);
        asm volatile("s_waitcnt lgkmcnt(0)" ::: "memory");

        if (doA) {
            short8 pf0 = *(const short8*)&PwA[(size_t)l16 * LDPP + quad * 8];
            short8 pf1 = *(const short8*)&PwA[(size_t)l16 * LDPP + 32 + quad * 8];
            #pragma unroll
            for (int dt = 0; dt < 4; ++dt) {
                oA[dt] = __builtin_amdgcn_mfma_f32_16x16x32_bf16(pf0, vf[dt][0], oA[dt], 0, 0, 0);
                oA[dt] = __builtin_amdgcn_mfma_f32_16x16x32_bf16(pf1, vf[dt][1], oA[dt], 0, 0, 0);
            }
        }
        {
            short8 pf0 = *(const short8*)&PwB[(size_t)l16 * LDPP + quad * 8];
            short8 pf1 = *(const short8*)&PwB[(size_t)l16 * LDPP + 32 + quad * 8];
            #pragma unroll
            for (int dt = 0; dt < 4; ++dt) {
                oB[dt] = __builtin_amdgcn_mfma_f32_16x16x32_bf16(pf0, vf[dt][0], oB[dt], 0, 0, 0);
                oB[dt] = __builtin_amdgcn_mfma_f32_16x16x32_bf16(pf1, vf[dt][1], oB[dt], 0, 0, 0);
            }
        }
        // no barrier in loop: P regions are per-wave
    }

    // per-half row totals (row = l16): reduce across quads
    lA += __shfl_xor(lA, 16); lA += __shfl_xor(lA, 32);
    lB += __shfl_xor(lB, 16); lB += __shfl_xor(lB, 32);

    // combine halves: fixed m_hat => partials add directly
    __syncthreads();          // both waves done with sm.P before comb overwrites it
    if (half) {
        float* cb = &sm.comb[lane][0];
        #pragma unroll
        for (int dt = 0; dt < 4; ++dt)
            #pragma unroll
            for (int r = 0; r < 4; ++r) {
                cb[dt * 4 + r]      = oA[dt][r];
                cb[16 + dt * 4 + r] = oB[dt][r];
            }
        cb[32] = lA; cb[33] = lB;
    }
    __syncthreads();
    if (half) return;

    {
        const float* cb = &sm.comb[lane][0];
        #pragma unroll
        for (int dt = 0; dt < 4; ++dt)
            #pragma unroll
            for (int r = 0; r < 4; ++r) {
                oA[dt][r] += cb[dt * 4 + r];
                oB[dt][r] += cb[16 + dt * 4 + r];
            }
        lA += cb[32]; lB += cb[33];
    }

    // invert per-lane (row l16), then gather to C-rows (quad*4+r)
    const float iA = 1.f / lA, iB = 1.f / lB;
    float irA[4], irB[4];
    #pragma unroll
    for (int r = 0; r < 4; ++r) {
        const int src = (lane & 48) | (quad * 4 + r);
        irA[r] = __shfl(iA, src);
        irB[r] = __shfl(iB, src);
    }

    // epilogue: normalize and write
    const int h = bh & 15, b = bh >> 4;
    #pragma unroll
    for (int dt = 0; dt < 4; ++dt)
        #pragma unroll
        for (int r = 0; r < 4; ++r) {
            const int rowA = qA * 64 + w4 * 16 + quad * 4 + r;
            const int rowB = qB * 64 + w4 * 16 + quad * 4 + r;
            const int col = h * 64 + dt * 16 + l16;
            Z[((size_t)b * T_SEQ + rowA) * D_MODEL + col] = f2bf(oA[dt][r] * irA[r]);
            Z[((size_t)b * T_SEQ + rowB) * D_MODEL + col] = f2bf(oB[dt][r] * irB[r]);
        }
}

// ---------------- launcher ----------------
extern "C" void kernel_launch(void* const* d_in, const int* in_sizes, int n_in,
                              void* d_out, int out_size, void* d_ws, size_t ws_size,
                              hipStream_t stream) {
    const float* x    = (const float*)d_in[0];
    const float* cosp = (const float*)d_in[1];
    const float* sinp = (const float*)d_in[2];
    const float* Wq   = (const float*)d_in[3];
    const float* Wk   = (const float*)d_in[4];
    const float* Wv   = (const float*)d_in[5];
    const float* Wo   = (const float*)d_in[6];

    char* w = (char*)d_ws;
    unsigned short* xb  = (unsigned short*)w; w += (size_t)M_TOT * D_MODEL * 2;    // 8 MB
    unsigned short* wt  = (unsigned short*)w; w += (size_t)4 * D_MODEL * D_MODEL * 2; // 8 MB (q,k,v,o)
    unsigned short* Qb  = (unsigned short*)w; w += (size_t)M_TOT * D_MODEL * 2;    // 8 MB
    unsigned short* Kb  = (unsigned short*)w; w += (size_t)M_TOT * D_MODEL * 2;
    unsigned short* Vtb = (unsigned short*)w; w += (size_t)M_TOT * D_MODEL * 2;    // [bh][d][t]
    unsigned short* Zb  = (unsigned short*)w; w += (size_t)M_TOT * D_MODEL * 2;
    float*          Ks  = (float*)w;          w += 32 * 8 * sizeof(float);         // Kseg[bh][8]

    convert_x_kernel<<<(M_TOT * D_MODEL) / 1024, 256, 0, stream>>>(x, xb);
    transpose_w_kernel<<<dim3(16, 16, 4), 256, 0, stream>>>(Wq, Wk, Wv, Wo, wt);

    // fused QKV projection; epilogue: z=0 Q(RoPE,*0.125), z=1 K(RoPE), z=2 V(transposed)
    gemm_kernel<4, 1><<<dim3(M_TOT / 128, D_MODEL / 128, 3), 256, 0, stream>>>(
        xb, wt, (void*)Qb, cosp, sinp);

    kmax_kernel<<<dim3(8, 32), 256, 0, stream>>>(Kb, Ks);

    // 128-thr blocks (2 waves: j-parity pair for one w4 slice), grid 2048 = 8 blocks/CU
    attn_kernel<<<2048, 128, 0, stream>>>(Qb, Kb, Vtb, Ks, Zb);

    // out projection -> fp32 d_out
    gemm_kernel<2, 0><<<dim3(M_TOT / 64, D_MODEL / 128, 1), 256, 0, stream>>>(
        Zb, wt + (size_t)3 * D_MODEL * D_MODEL, d_out, nullptr, nullptr);
}